// Round 1
// 205.589 us; speedup vs baseline: 1.0014x; 1.0014x over previous
//
#include <hip/hip_runtime.h>

// YOLO loss reduction: B=512, 3136 cells/sample, 15 slots/cell, fp32, sum.
//
// R1 LDS-tile 75us. R2 cell/thread 116us. R3 slot-stream 84us. R4 1-wave DMA
// 95us. R5 fast-math slot-stream 76us. R6 batch-8 load/compute phase split:
// 72us kernel — but VGPR=60 proves the compiler re-serialized the 32-load
// phase (needs ~80 VGPR), and dispatch-124 (0 HBM traffic, same 71.7us)
// proves we're NOT BW-bound.
// R7: occupancy-quantization fix. 2940 blocks vs 2048 resident (8/CU at
//    VGPR<=64) ran as two machine waves -> 72% utilization. New shape:
//    grid 1960 x 256thr x 12 float4/thread = n4 exactly; 1960 <= 2048 so
//    ALL blocks resident from t=0 (single wave, no refill). Depth-2
//    rotating pipeline (load k+1 while computing k), fully unrolled so
//    buffer indices are compile-time constants (no scratch).

#define EPSF 1e-9f
#define LN2F 0.69314718055994530942f
#define ITERS 12

__device__ __forceinline__ float bce_of(float ox, float tx) {
    const float l1 = __log2f(ox + EPSF);
    const float l2 = __log2f((1.f - ox) + EPSF);
    return -LN2F * (tx * l1 + (1.f - tx) * l2);
}

// ---------- fast path: grid*256*12 == n4 exactly, no guards ----------
__global__ __launch_bounds__(256, 8) void yolo_loss_fast(
    const float* __restrict__ o, const float* __restrict__ t,
    float* __restrict__ out_sum)
{
    const int tid = threadIdx.x;
    const unsigned T   = gridDim.x * 256u;
    const unsigned idx = blockIdx.x * 256u + (unsigned)tid;
    const float4* o4 = (const float4*)o;
    const float4* t4 = (const float4*)t;

    // depth-2 rotating buffers: ~20 live VGPRs, honest vs the 64-reg budget
    float4 ob[2], tb[2];
    float  gl[2], gh[2];
    unsigned sl[2];

    // prologue: iteration 0 -> slot 0
    {
        const unsigned i  = idx;
        const unsigned e0 = i * 4u;
        const unsigned c0 = e0 / 15u;            // magic-mul div
        const unsigned c3 = (e0 + 3u) / 15u;
        sl[0] = e0 - c0 * 15u;
        ob[0] = o4[i];
        tb[0] = t4[i];
        gl[0] = o[c0 * 15u];                     // gate gathers: L1-hot
        gh[0] = o[c3 * 15u];
    }

    float acc = 0.f;
    #pragma unroll
    for (int k = 0; k < ITERS; ++k) {
        const int cur = k & 1;
        const int nxt = cur ^ 1;

        // ---- issue next iteration's loads before consuming current ----
        if (k + 1 < ITERS) {
            const unsigned i  = idx + (unsigned)(k + 1) * T;
            const unsigned e0 = i * 4u;
            const unsigned c0 = e0 / 15u;
            const unsigned c3 = (e0 + 3u) / 15u;
            sl[nxt] = e0 - c0 * 15u;
            ob[nxt] = o4[i];
            tb[nxt] = t4[i];
            gl[nxt] = o[c0 * 15u];
            gh[nxt] = o[c3 * 15u];
        }

        // ---- compute slot `cur` ----
        const unsigned s0 = sl[cur];
        const float glo = gl[cur], ghi = gh[cur];
        const float oe[4] = {ob[cur].x, ob[cur].y, ob[cur].z, ob[cur].w};
        const float te[4] = {tb[cur].x, tb[cur].y, tb[cur].z, tb[cur].w};

        // slot-4 (confidence) element: at most one per float4 -> 1 BCE, not 4
        bool is4[4];
        #pragma unroll
        for (int j = 0; j < 4; ++j) {
            const unsigned s = s0 + (unsigned)j;
            is4[j] = (s == 4u) | (s == 19u);
        }
        float oc = oe[3], tc = te[3];
        #pragma unroll
        for (int j = 2; j >= 0; --j) { oc = is4[j] ? oe[j] : oc; tc = is4[j] ? te[j] : tc; }
        const float bce = bce_of(oc, tc);        // garbage-in-safe: inputs in (0,1)

        #pragma unroll
        for (int j = 0; j < 4; ++j) {
            unsigned s = s0 + (unsigned)j;
            const bool wrap = s >= 15u;
            s = wrap ? s - 15u : s;
            const float gate = wrap ? ghi : glo;
            const float ox = oe[j], tx = te[j];

            const float d  = ox - tx;
            const float sq = d * d;
            const float s23 = (ox + tx) - 2.f * __builtin_amdgcn_sqrtf(ox * tx);

            float c = ((s == 2u) | (s == 3u)) ? s23 : sq;
            c = is4[j] ? bce : c;
            c = ((s == 1u) | (s == 14u)) ? 0.f : c;
            c = (gate != 0.f) ? c : 0.f;
            acc += c;
        }
    }

    #pragma unroll
    for (int off = 32; off; off >>= 1) acc += __shfl_down(acc, off, 64);
    __shared__ float wsum[4];
    if ((tid & 63) == 0) wsum[tid >> 6] = acc;
    __syncthreads();
    if (tid == 0) atomicAdd(out_sum, wsum[0] + wsum[1] + wsum[2] + wsum[3]);
}

// ---------- generic fallback (any n): R5-style guarded grid-stride ----------
__global__ __launch_bounds__(256) void yolo_loss_generic(
    const float* __restrict__ o, const float* __restrict__ t,
    float* __restrict__ out_sum, int n4, int n)
{
    const int tid = threadIdx.x;
    const int stride = gridDim.x * 256;
    const float4* o4 = (const float4*)o;
    const float4* t4 = (const float4*)t;
    float acc = 0.f;

    for (int i = blockIdx.x * 256 + tid; i < n4; i += stride) {
        const float4 ov = o4[i];
        const float4 tv = t4[i];
        const unsigned e0 = (unsigned)i * 4u;
        const unsigned c0 = e0 / 15u;
        const unsigned c3 = (e0 + 3u) / 15u;
        const unsigned s0 = e0 - c0 * 15u;
        const float glo = o[c0 * 15u], ghi = o[c3 * 15u];
        const float oe[4] = {ov.x, ov.y, ov.z, ov.w};
        const float te[4] = {tv.x, tv.y, tv.z, tv.w};
        #pragma unroll
        for (int j = 0; j < 4; ++j) {
            unsigned s = s0 + (unsigned)j;
            const bool wrap = s >= 15u;
            s = wrap ? s - 15u : s;
            const float gate = wrap ? ghi : glo;
            const float ox = oe[j], tx = te[j];
            const float d = ox - tx;
            const float sq = d * d;
            const float s23 = (ox + tx) - 2.f * __builtin_amdgcn_sqrtf(ox * tx);
            float c = ((s == 2u) | (s == 3u)) ? s23 : sq;
            c = (s == 4u) ? bce_of(ox, tx) : c;
            c = ((s == 1u) | (s == 14u)) ? 0.f : c;
            c = (gate != 0.f) ? c : 0.f;
            acc += c;
        }
    }
    const int tail0 = n4 * 4;
    if (blockIdx.x == 0 && tid < n - tail0) {
        const unsigned e = (unsigned)(tail0 + tid);
        const unsigned cell = e / 15u;
        const unsigned s = e - cell * 15u;
        const float gate = o[cell * 15u];
        const float ox = o[e], tx = t[e];
        const float d = ox - tx;
        float c = d * d;
        c = ((s == 2u) | (s == 3u)) ? (ox + tx) - 2.f * __builtin_amdgcn_sqrtf(ox * tx) : c;
        c = (s == 4u) ? bce_of(ox, tx) : c;
        c = ((s == 1u) | (s == 14u)) ? 0.f : c;
        c = (gate != 0.f) ? c : 0.f;
        acc += c;
    }
    #pragma unroll
    for (int off = 32; off; off >>= 1) acc += __shfl_down(acc, off, 64);
    __shared__ float wsum[4];
    if ((tid & 63) == 0) wsum[tid >> 6] = acc;
    __syncthreads();
    if (tid == 0) atomicAdd(out_sum, wsum[0] + wsum[1] + wsum[2] + wsum[3]);
}

extern "C" void kernel_launch(void* const* d_in, const int* in_sizes, int n_in,
                              void* d_out, int out_size, void* d_ws, size_t ws_size,
                              hipStream_t stream) {
    const float* o = (const float*)d_in[0];
    const float* t = (const float*)d_in[1];
    float* out = (float*)d_out;
    const int n = in_sizes[0];
    const int n4 = n / 4;

    // d_out is poisoned 0xAA before every timed replay -> zero it on-stream.
    hipMemsetAsync(out, 0, sizeof(float), stream);

    const int per_block = 256 * ITERS;           // 3072 float4s per block
    if ((n % 4 == 0) && (n4 > 0) && (n4 % per_block == 0) && (n4 / per_block <= 2048)) {
        // ref shape: n4 = 6,021,120 -> grid 1960 (all resident: 8 blk/CU cap)
        const int grid = n4 / per_block;
        yolo_loss_fast<<<grid, 256, 0, stream>>>(o, t, out);
    } else {
        yolo_loss_generic<<<2940, 256, 0, stream>>>(o, t, out, n4, n);
    }
}